// Round 6
// baseline (115.444 us; speedup 1.0000x reference)
//
#include <hip/hip_runtime.h>

// RGate: apply Rx(angle[i]) to every qubit of a 22-qubit statevector.
// Gate on amp-bit k pairs indices at stride 2^k and uses angle[21-k].
//
// R5 rocprof: 64KB-tile pass = 47 us @ 1.06 TB/s, VALU 18%, occ 38% ->
// latency/barrier-bound, NOT BW-bound. Redesign for overlap:
//   Pass A (bits 0-11): 4096-amp tile, 32 KB LDS, 5 blocks/CU. ONE barrier:
//     load(reg {0,1,8,9}) -> wave-local re-tile (bits 2-5, lgkmcnt only,
//     no __syncthreads: waves are lockstep) -> block re-tile (bits 6,7,10,11).
//   Pass B (bits 12-16): ZERO LDS/barriers. reg j = bits 12-15, lane bit 5 =
//     bit 16 (gate via shfl_xor 32). Lanes cover 2 full 128B lines/instr.
//   Pass C (bits 17-21): same template, bits 17-20 reg + bit 21 shfl.
// Traffic 3 x 67 MB = 201 MB; each pass should run near BW floor (~11 us).

constexpr int NTOT = 1 << 22;   // 2^22 amplitudes

__device__ __forceinline__ void rotg(float& ar, float& ai, float& br, float& bi,
                                     float c, float s) {
    // a' = c*a - i*s*b ; b' = c*b - i*s*a
    float t0 = ar, t1 = ai, t2 = br, t3 = bi;
    ar = fmaf(c, t0,  s * t3);
    ai = fmaf(c, t1, -s * t2);
    br = fmaf(c, t2,  s * t1);
    bi = fmaf(c, t3, -s * t0);
}

// NB butterfly gates for amp bits K0..K0+NB-1, amp bit (K0+b) at register-
// index bit (MSH+b). Angles wave-uniform.
template<int K0, int NB, int MSH>
__device__ __forceinline__ void gatesM(float (&ar)[16], float (&ai)[16],
                                       const float* __restrict__ ang) {
    #pragma unroll
    for (int b = 0; b < NB; ++b) {
        const int m = 1 << (MSH + b);
        float c, s;
        sincosf(0.5f * ang[21 - (K0 + b)], &s, &c);
        #pragma unroll
        for (int j = 0; j < 16; ++j)
            if (!(j & m)) rotg(ar[j], ai[j], ar[j | m], ai[j | m], c, s);
    }
}

// Cross-lane gate: partner = lane ^ XOR. Symmetric update valid on both sides:
// x_r' = c*x_r + s*p_i ; x_i' = c*x_i - s*p_r.
template<int XOR>
__device__ __forceinline__ void shflgate(float (&ar)[16], float (&ai)[16],
                                         float c, float s) {
    #pragma unroll
    for (int j = 0; j < 16; ++j) {
        float pr = __shfl_xor(ar[j], XOR, 64);
        float pi = __shfl_xor(ai[j], XOR, 64);
        ar[j] = fmaf(c, ar[j],  s * pi);
        ai[j] = fmaf(c, ai[j], -s * pr);
    }
}

// LDS bank swizzle (float2 elements, bank-pair = idx&15): XOR bits 4-7 into
// 0-3. For all three arrangements below, each instr's 64 lanes cover all 16
// bank-pairs exactly 4x (verified per-arrangement) = b64 floor.
__device__ __forceinline__ int slot(int i) { return i ^ ((i >> 4) & 15); }

// ---------------- Pass A: bits 0..11, tile = 4096 contiguous ---------------
// 256 thr (4 waves), 16 amps/thread, LDS 32 KB -> 5 blocks/CU.
// Tile-local index i (12 bits), lane l = t&63, wave w = t>>6:
//  arr1 (load):  i = (w<<10)|(q<<8)|(l<<2)|r   reg {0,1 | 8,9}; gates 0,1,8,9
//  arr2 (wave-local): i = (w<<10)|((l>>2)<<6)|(j<<2)|(l&3)
//                reg = i bits 2-5; gates 2-5.  NO barrier (lgkmcnt only).
//  arr3 (block): i = ((j>>2)<<10)|(w<<8)|((j&3)<<6)|l
//                reg = {6,7 | 10,11}; gates 6,7,10,11. ONE barrier. Store.
__global__ __launch_bounds__(256) void rgate_A(const float* __restrict__ xr,
                                               const float* __restrict__ xi,
                                               const float* __restrict__ ang,
                                               float* __restrict__ out) {
    __shared__ float2 sv[4096];          // 32 KB
    const int t = threadIdx.x;
    const int l = t & 63, w = t >> 6;
    const int g0 = blockIdx.x << 12;

    float ar[16], ai[16];
    #pragma unroll
    for (int q = 0; q < 4; ++q) {
        const int i = (w << 10) | (q << 8) | (l << 2);
        float4 vr = *(const float4*)(xr + g0 + i);
        float4 vi = *(const float4*)(xi + g0 + i);
        ar[4*q+0] = vr.x; ar[4*q+1] = vr.y; ar[4*q+2] = vr.z; ar[4*q+3] = vr.w;
        ai[4*q+0] = vi.x; ai[4*q+1] = vi.y; ai[4*q+2] = vi.z; ai[4*q+3] = vi.w;
    }
    gatesM<0, 2, 0>(ar, ai, ang);        // amp bits 0,1 (reg bits 0,1 = r)
    gatesM<8, 2, 2>(ar, ai, ang);        // amp bits 8,9 (reg bits 2,3 = q)

    #pragma unroll
    for (int q = 0; q < 4; ++q)
        #pragma unroll
        for (int r = 0; r < 4; ++r)
            sv[slot((w << 10) | (q << 8) | (l << 2) | r)]
                = make_float2(ar[4*q+r], ai[4*q+r]);

    // wave-local re-tile: same-wave data only -> LDS drain, no __syncthreads
    __asm__ volatile("s_waitcnt lgkmcnt(0)" ::: "memory");

    const int b2 = (w << 10) | ((l >> 2) << 6) | (l & 3);
    #pragma unroll
    for (int j = 0; j < 16; ++j) {
        float2 v = sv[slot(b2 | (j << 2))];
        ar[j] = v.x; ai[j] = v.y;
    }
    gatesM<2, 4, 0>(ar, ai, ang);        // amp bits 2-5
    #pragma unroll
    for (int j = 0; j < 16; ++j)
        sv[slot(b2 | (j << 2))] = make_float2(ar[j], ai[j]);
    __syncthreads();                     // the single block-level exchange

    const int b3 = (w << 8) | l;
    #pragma unroll
    for (int j = 0; j < 16; ++j) {
        float2 v = sv[slot(b3 | ((j & 3) << 6) | ((j >> 2) << 10))];
        ar[j] = v.x; ai[j] = v.y;
    }
    gatesM<6, 2, 0>(ar, ai, ang);        // amp bits 6,7  (reg bits 0,1)
    gatesM<10, 2, 2>(ar, ai, ang);       // amp bits 10,11 (reg bits 2,3)

    #pragma unroll
    for (int j = 0; j < 16; ++j) {
        const int i = b3 | ((j & 3) << 6) | ((j >> 2) << 10);
        out[g0 + i]        = ar[j];      // per-j: 64 lanes x 4B = 256B contig
        out[NTOT + g0 + i] = ai[j];
    }
}

// ---------------- Passes B/C: streaming strided, zero LDS ------------------
// reg j = amp bits KJ..KJ+3 (4 gates); lane bit 5 = amp bit KU (1 shfl gate).
// base bits: 0-4 = t&31 (contig 128B), 5-6 = t>>6, 7.. = blockIdx (+VS high
// part). Per instr: 2 full 128B lines (lanes 0-31, 32-63 at +2^KU).
template<int KJ, int KU, int BL, int VS>
__global__ __launch_bounds__(256) void rgate_s(const float* __restrict__ ang,
                                               float* __restrict__ out) {
    const int t = threadIdx.x, b = blockIdx.x;
    const int base = (t & 31) | (((t >> 5) & 1) << KU) | ((t >> 6) << 5)
                   | ((b & ((1 << BL) - 1)) << 7) | ((b >> BL) << VS);
    float* outr = out;
    float* outi = out + NTOT;

    float ar[16], ai[16];
    #pragma unroll
    for (int j = 0; j < 16; ++j) ar[j] = outr[base + (j << KJ)];
    #pragma unroll
    for (int j = 0; j < 16; ++j) ai[j] = outi[base + (j << KJ)];

    gatesM<KJ, 4, 0>(ar, ai, ang);       // amp bits KJ..KJ+3
    {
        float c, s;
        sincosf(0.5f * ang[21 - KU], &s, &c);
        shflgate<32>(ar, ai, c, s);      // amp bit KU (lane bit 5)
    }

    #pragma unroll
    for (int j = 0; j < 16; ++j) outr[base + (j << KJ)] = ar[j];
    #pragma unroll
    for (int j = 0; j < 16; ++j) outi[base + (j << KJ)] = ai[j];
}

extern "C" void kernel_launch(void* const* d_in, const int* in_sizes, int n_in,
                              void* d_out, int out_size, void* d_ws, size_t ws_size,
                              hipStream_t stream) {
    const float* xr  = (const float*)d_in[0];
    const float* xi  = (const float*)d_in[1];
    const float* ang = (const float*)d_in[2];
    float* out = (float*)d_out;

    // Pass A: bits 0-11, d_in -> d_out (fully overwrites d_out)
    rgate_A<<<1024, 256, 0, stream>>>(xr, xi, ang, out);
    // Pass B: bits 12-16 (reg 12-15 + shfl bit 16), in-place
    rgate_s<12, 16, 5, 17><<<1024, 256, 0, stream>>>(ang, out);
    // Pass C: bits 17-21 (reg 17-20 + shfl bit 21), in-place
    rgate_s<17, 21, 10, 27><<<1024, 256, 0, stream>>>(ang, out);
}

// Round 7
// 109.881 us; speedup vs baseline: 1.0506x; 1.0506x over previous
//
#include <hip/hip_runtime.h>

// RGate: apply Rx(angle[i]) to every qubit of a 22-qubit statevector.
// Gate on amp-bit k pairs indices at stride 2^k and uses angle[21-k].
//
// Session accounting (R5 direct measurement): dur_us = ~43 us harness fill
// + sum of pass times. Strided pass B (1 retile) ~= 16.6 us; old contiguous
// pass A (3 retiles / 3 barriers) = 47 us, latency-bound (13% HBM, 18% VALU,
// 38% occ, 262K LDS-conflict cycles). This version: pass A with ONE barrier,
// ONE LDS round-trip, 6 shfl gates; pass B verbatim from the measured build.
//   Pass A: bits 0-12. Phase 1: gates {0,1}(reg r) {2-7}(shfl) {10,11}(reg q).
//           LDS exchange (1 barrier). Phase 2: gates {8,9}(reg j) {12}(shfl32).
//   Pass B: bits 13-21, tile 512H x 16l, 1 retile + shfl for bit 17.

constexpr int NTOT = 1 << 22;   // 2^22 amplitudes

__device__ __forceinline__ void rotg(float& ar, float& ai, float& br, float& bi,
                                     float c, float s) {
    // a' = c*a - i*s*b ; b' = c*b - i*s*a
    float t0 = ar, t1 = ai, t2 = br, t3 = bi;
    ar = fmaf(c, t0,  s * t3);
    ai = fmaf(c, t1, -s * t2);
    br = fmaf(c, t2,  s * t1);
    bi = fmaf(c, t3, -s * t0);
}

// NB butterfly gates for amp bits K0..K0+NB-1; amp bit (K0+b) lives at
// register-index bit (MSH+b). Angles wave-uniform.
template<int K0, int NB, int MSH>
__device__ __forceinline__ void gatesM(float (&ar)[16], float (&ai)[16],
                                       const float* __restrict__ ang) {
    #pragma unroll
    for (int b = 0; b < NB; ++b) {
        const int m = 1 << (MSH + b);
        float c, s;
        sincosf(0.5f * ang[21 - (K0 + b)], &s, &c);
        #pragma unroll
        for (int j = 0; j < 16; ++j)
            if (!(j & m)) rotg(ar[j], ai[j], ar[j | m], ai[j | m], c, s);
    }
}

// Cross-lane gate: partner = lane ^ XOR. Symmetric update valid on both sides:
// x_r' = c*x_r + s*p_i ; x_i' = c*x_i - s*p_r.
template<int XOR>
__device__ __forceinline__ void shflgate(float (&ar)[16], float (&ai)[16],
                                         float c, float s) {
    #pragma unroll
    for (int j = 0; j < 16; ++j) {
        float pr = __shfl_xor(ar[j], XOR, 64);
        float pi = __shfl_xor(ai[j], XOR, 64);
        ar[j] = fmaf(c, ar[j],  s * pi);
        ai[j] = fmaf(c, ai[j], -s * pr);
    }
}

// LDS swizzle (float2 elems, bank-pair = idx&15): XOR idx bits 4-7 into 0-3.
// Both pass-A arrangements verified at the b64 4-lane/bank-pair floor.
__device__ __forceinline__ int slot(int i) { return i ^ ((i >> 4) & 15); }

// ---------------- Pass A: bits 0..12, tile = 8192 contiguous ---------------
// 512 thr (8 waves, w=t>>6), 16 amps/thread, LDS 8192 float2 = 64 KB.
// Phase 1 (load, i1 = r | l<<2 | (w&3)<<8 | q<<10 | (w>>2)<<12):
//   per-instr 64 lanes x 16B = 1 KB contiguous loads. Gates: 0,1 (r);
//   2-7 (shfl_xor 1..32 on lane bits); 10,11 (q).
// LDS write -> ONE __syncthreads -> read at
//   i2 = r | (l&15)<<2 | ((l>>4)&1)<<6 | (w&1)<<7 | j<<8 | (w>>1)<<10 | (l>>5)<<12
// Phase 2: gates 8,9 (j); 12 (shfl_xor 32). float4 stores, two 512B segs/instr.
__global__ __launch_bounds__(512) void rgate_A(const float* __restrict__ xr,
                                               const float* __restrict__ xi,
                                               const float* __restrict__ ang,
                                               float* __restrict__ out) {
    __shared__ float2 sv[8192];          // 64 KB
    const int t = threadIdx.x;
    const int l = t & 63, w = t >> 6;
    const int g0 = blockIdx.x << 13;

    const int base1 = (l << 2) | ((w & 3) << 8) | ((w >> 2) << 12);

    float ar[16], ai[16];
    #pragma unroll
    for (int q = 0; q < 4; ++q) {
        const int i = base1 | (q << 10);
        float4 vr = *(const float4*)(xr + g0 + i);
        float4 vi = *(const float4*)(xi + g0 + i);
        ar[4*q+0] = vr.x; ar[4*q+1] = vr.y; ar[4*q+2] = vr.z; ar[4*q+3] = vr.w;
        ai[4*q+0] = vi.x; ai[4*q+1] = vi.y; ai[4*q+2] = vi.z; ai[4*q+3] = vi.w;
    }
    gatesM<0, 2, 0>(ar, ai, ang);        // amp bits 0,1  (reg bits 0,1 = r)
    gatesM<10, 2, 2>(ar, ai, ang);       // amp bits 10,11 (reg bits 2,3 = q)

    {   // amp bits 2-7 = lane bits 0-5: six cross-lane gates
        float c, s;
        sincosf(0.5f * ang[21 - 2], &s, &c); shflgate< 1>(ar, ai, c, s);
        sincosf(0.5f * ang[21 - 3], &s, &c); shflgate< 2>(ar, ai, c, s);
        sincosf(0.5f * ang[21 - 4], &s, &c); shflgate< 4>(ar, ai, c, s);
        sincosf(0.5f * ang[21 - 5], &s, &c); shflgate< 8>(ar, ai, c, s);
        sincosf(0.5f * ang[21 - 6], &s, &c); shflgate<16>(ar, ai, c, s);
        sincosf(0.5f * ang[21 - 7], &s, &c); shflgate<32>(ar, ai, c, s);
    }

    #pragma unroll
    for (int q = 0; q < 4; ++q)
        #pragma unroll
        for (int r = 0; r < 4; ++r)
            sv[slot(base1 | (q << 10) | r)] = make_float2(ar[4*q+r], ai[4*q+r]);
    __syncthreads();                     // the single block-level exchange

    const int base2 = ((l & 15) << 2) | (((l >> 4) & 1) << 6) | ((w & 1) << 7)
                    | ((w >> 1) << 10) | ((l >> 5) << 12);
    #pragma unroll
    for (int j = 0; j < 4; ++j)
        #pragma unroll
        for (int r = 0; r < 4; ++r) {
            float2 v = sv[slot(base2 | (j << 8) | r)];
            ar[4*j+r] = v.x; ai[4*j+r] = v.y;
        }
    gatesM<8, 2, 2>(ar, ai, ang);        // amp bits 8,9 (reg bits 2,3 = j)
    {   // amp bit 12 = lane bit 5
        float c, s;
        sincosf(0.5f * ang[21 - 12], &s, &c);
        shflgate<32>(ar, ai, c, s);
    }

    #pragma unroll
    for (int j = 0; j < 4; ++j) {
        const int i = base2 | (j << 8);
        *(float4*)(out + g0 + i)        = make_float4(ar[4*j], ar[4*j+1], ar[4*j+2], ar[4*j+3]);
        *(float4*)(out + NTOT + g0 + i) = make_float4(ai[4*j], ai[4*j+1], ai[4*j+2], ai[4*j+3]);
    }
}

// ---------------- Pass B: bits 13..21 (h stride 8192) ----------------------
// Verbatim from the measured-fast build (~16.6 us inferred).
// amp = h*8192 + l, h in [0,512); tile = all h x 16 contiguous l = 64 KB.
// 512 threads, 16 amps/thread. sub = t&15, hw = t>>4 in [0,32).
//  B1 (load):  h = j | (hw<<4) -> reg = h bits 0..3 -> gates 13-16;
//              then gate 17 (h bit 4 = lane bit 4) via __shfl_xor(.,16)
//  B2 (store): h = hw | (j<<5) -> reg = h bits 5..8 -> gates 18-21
// LDS sv[h*16+sub]: both arrangements conflict-free. XCD-contiguous remap.
__global__ __launch_bounds__(512, 4) void rgate_B(const float* __restrict__ ang,
                                                  float* __restrict__ out) {
    __shared__ float2 sv[8192];          // 64 KB
    const int t   = threadIdx.x;
    const int bid = blockIdx.x;
    const int blk = (bid >> 3) | ((bid & 7) << 6);   // XCD-contiguous remap
    const int sub = t & 15, hw = t >> 4;
    const int lbase = (blk << 4) + sub;
    float* outr = out;
    float* outi = out + NTOT;

    float ar[16], ai[16];
    #pragma unroll
    for (int j = 0; j < 16; ++j) {
        const int g = ((j | (hw << 4)) << 13) + lbase;
        ar[j] = outr[g]; ai[j] = outi[g];
    }
    gatesM<13, 4, 0>(ar, ai, ang);       // gates 13-16

    {   // gate 17: partner = lane^16 (same wave)
        float c, s;
        sincosf(0.5f * ang[21 - 17], &s, &c);
        shflgate<16>(ar, ai, c, s);
    }

    #pragma unroll
    for (int j = 0; j < 16; ++j)
        sv[((j | (hw << 4)) << 4) + sub] = make_float2(ar[j], ai[j]);
    __syncthreads();

    #pragma unroll
    for (int j = 0; j < 16; ++j) {
        float2 v = sv[((hw | (j << 5)) << 4) + sub];
        ar[j] = v.x; ai[j] = v.y;
    }
    gatesM<18, 4, 0>(ar, ai, ang);       // gates 18-21

    #pragma unroll
    for (int j = 0; j < 16; ++j) {
        const int g = ((hw | (j << 5)) << 13) + lbase;
        outr[g] = ar[j]; outi[g] = ai[j];
    }
}

extern "C" void kernel_launch(void* const* d_in, const int* in_sizes, int n_in,
                              void* d_out, int out_size, void* d_ws, size_t ws_size,
                              hipStream_t stream) {
    const float* xr  = (const float*)d_in[0];
    const float* xi  = (const float*)d_in[1];
    const float* ang = (const float*)d_in[2];
    float* out = (float*)d_out;

    // Pass A: bits 0-12, d_in -> d_out (fully overwrites d_out)
    rgate_A<<<512, 512, 0, stream>>>(xr, xi, ang, out);
    // Pass B: bits 13-21, in-place on d_out
    rgate_B<<<512, 512, 0, stream>>>(ang, out);
}